// Round 7
// baseline (402.328 us; speedup 1.0000x reference)
//
#include <hip/hip_runtime.h>
#include <math.h>

// Problem constants: B=4, S=1024, D=512, H=8, HD=64, HID=2048
#define kB 4
#define kS 1024
#define kD 512
#define kH 8
#define kHD 64
#define kHID 2048
#define kNT (kB * kS)          // 4096 tokens
#define kBSD (kNT * kD)        // 2,097,152

typedef __attribute__((ext_vector_type(8))) short bf16x8;
typedef __attribute__((ext_vector_type(4))) float f32x4;

#define AS1 __attribute__((address_space(1)))
#define AS3 __attribute__((address_space(3)))

__device__ __forceinline__ float bf2f(unsigned short u) {
  return __uint_as_float(((unsigned int)u) << 16);
}
__device__ __forceinline__ unsigned short f2bf(float f) {
  unsigned int u = __float_as_uint(f);
  u += 0x7fffu + ((u >> 16) & 1u);   // RNE
  return (unsigned short)(u >> 16);
}
__device__ __forceinline__ unsigned int pack2(unsigned short a, unsigned short b) {
  return (unsigned)a | ((unsigned)b << 16);
}

#define BARC() do { asm volatile("" ::: "memory"); __builtin_amdgcn_s_barrier(); asm volatile("" ::: "memory"); } while (0)

// ---------------------------------------------------------------------------
// Fused build A: QKV (head-permuted) + O (standard cat) + biases + LN1.
// grid 5128 x 256:
//   blocks [0,4096):    weights, seg = gid>>18: 0=q,1=k,2=v (perm), 3=o (std)
//   blocks [4096,4104): biases (2048 threads over 4 segments)
//   blocks [4104,5128): LN1 (one wave per token, 4 tokens/block)
// ---------------------------------------------------------------------------
__global__ __launch_bounds__(256) void build_wA_kernel(
    const float* __restrict__ qlm, const float* __restrict__ qph,
    const float* __restrict__ klm, const float* __restrict__ kph,
    const float* __restrict__ vlm, const float* __restrict__ vph,
    const float* __restrict__ olm, const float* __restrict__ oph,
    const float* __restrict__ qbm, const float* __restrict__ qbp,
    const float* __restrict__ kbm, const float* __restrict__ kbp,
    const float* __restrict__ vbm, const float* __restrict__ vbp,
    const float* __restrict__ obm, const float* __restrict__ obp,
    const float* __restrict__ xr, const float* __restrict__ xi,
    const float* __restrict__ g_r, const float* __restrict__ g_i,
    const float* __restrict__ b_r, const float* __restrict__ b_i,
    unsigned short* __restrict__ Wqkv, unsigned short* __restrict__ Wo,
    float* __restrict__ qkvBias, float* __restrict__ oBias,
    unsigned short* __restrict__ H) {
  int bx = blockIdx.x;
  if (bx >= 4104) {
    // ---- LN1: one wave per token ----
    int w = threadIdx.x >> 6, lane = threadIdx.x & 63;
    int t = (bx - 4104) * 4 + w;
    int d0 = lane * 8;
    const float* xrt = xr + (size_t)t * 512 + d0;
    const float* xit = xi + (size_t)t * 512 + d0;
    float4 a0 = *(const float4*)&xrt[0];
    float4 a1 = *(const float4*)&xrt[4];
    float4 c0 = *(const float4*)&xit[0];
    float4 c1 = *(const float4*)&xit[4];
    float s1 = a0.x + a0.y + a0.z + a0.w + a1.x + a1.y + a1.z + a1.w;
    float s2 = c0.x + c0.y + c0.z + c0.w + c1.x + c1.y + c1.z + c1.w;
#pragma unroll
    for (int off = 1; off < 64; off <<= 1) {
      s1 += __shfl_xor(s1, off);
      s2 += __shfl_xor(s2, off);
    }
    float mr = s1 * (1.f / kD), mi = s2 * (1.f / kD);
    float ar[8] = {a0.x, a0.y, a0.z, a0.w, a1.x, a1.y, a1.z, a1.w};
    float ai[8] = {c0.x, c0.y, c0.z, c0.w, c1.x, c1.y, c1.z, c1.w};
    float v = 0.f;
#pragma unroll
    for (int e = 0; e < 8; e++) {
      float cr = ar[e] - mr, ci = ai[e] - mi;
      v += cr * cr + ci * ci;
    }
#pragma unroll
    for (int off = 1; off < 64; off <<= 1) v += __shfl_xor(v, off);
    float inv = rsqrtf(v * (1.f / kD) + 1e-6f);
    unsigned short pr[8], pi[8];
#pragma unroll
    for (int e = 0; e < 8; e++) {
      float nr = (ar[e] - mr) * inv;
      float ni = (ai[e] - mi) * inv;
      pr[e] = f2bf(nr * g_r[d0 + e] - ni * g_i[d0 + e] + b_r[d0 + e]);
      pi[e] = f2bf(nr * g_i[d0 + e] + ni * g_r[d0 + e] + b_i[d0 + e]);
    }
    unsigned short* ot = H + (size_t)t * 1024 + d0;
    *(bf16x8*)&ot[0] = *(const bf16x8*)pr;
    *(bf16x8*)&ot[512] = *(const bf16x8*)pi;
    return;
  }
  if (bx >= 4096) {
    int gid = (bx - 4096) * 256 + threadIdx.x;  // 0..2047
    int seg = gid >> 9, m = gid & 511;
    const float* bm = seg == 0 ? qbm : seg == 1 ? kbm : seg == 2 ? vbm : obm;
    const float* bp = seg == 0 ? qbp : seg == 1 ? kbp : seg == 2 ? vbp : obp;
    float s, c;
    __sincosf(bp[m], &s, &c);
    float br = bm[m] * c, bi = bm[m] * s;
    if (seg < 3) {
      int h = m >> 6, d = m & 63;
      qkvBias[seg * 1024 + h * 128 + d] = br;
      qkvBias[seg * 1024 + h * 128 + 64 + d] = bi;
    } else {
      oBias[m] = br;
      oBias[512 + m] = bi;
    }
    return;
  }
  int gid = bx * 256 + threadIdx.x;
  int seg = gid >> 18;
  int id = gid & 262143;
  const float* lm = seg == 0 ? qlm : seg == 1 ? klm : seg == 2 ? vlm : olm;
  const float* ph = seg == 0 ? qph : seg == 1 ? kph : seg == 2 ? vph : oph;
  float mm = __expf(lm[id]);
  float s, c;
  __sincosf(ph[id], &s, &c);
  float wr = mm * c, wi = mm * s;
  int m = id >> 9, k = id & 511;
  if (seg < 3) {
    int h = m >> 6, d = m & 63;
    size_t rowR = (size_t)seg * 1024 + h * 128 + d;
    size_t rowI = rowR + 64;
    Wqkv[rowR * 1024 + k] = f2bf(wr);
    Wqkv[rowR * 1024 + 512 + k] = f2bf(-wi);
    Wqkv[rowI * 1024 + k] = f2bf(wi);
    Wqkv[rowI * 1024 + 512 + k] = f2bf(wr);
  } else {
    Wo[(size_t)m * 1024 + k] = f2bf(wr);
    Wo[(size_t)m * 1024 + 512 + k] = f2bf(-wi);
    Wo[(size_t)(512 + m) * 1024 + k] = f2bf(wi);
    Wo[(size_t)(512 + m) * 1024 + 512 + k] = f2bf(wr);
  }
}

// ---------------------------------------------------------------------------
// Fused build B, 2 elements/thread, packed stores. grid 6144 x 256.
// seg = gid>>19: 0=gate,1=up,2=down.
// Wgu role-in-j: feature T -> row (T>>4)*64 + role*16 + (T&15).
// Wd: K interleaved (hr,hi) pairs.
// ---------------------------------------------------------------------------
__global__ __launch_bounds__(256) void build_wB_kernel(
    const float* __restrict__ glm, const float* __restrict__ gph,
    const float* __restrict__ ulm, const float* __restrict__ uph,
    const float* __restrict__ dlm, const float* __restrict__ dph,
    unsigned short* __restrict__ Wgu, unsigned short* __restrict__ Wd) {
  int gid = blockIdx.x * 256 + threadIdx.x;
  int seg = gid >> 19;
  int id0 = (gid & 524287) * 2;
  const float* lm = seg == 0 ? glm : seg == 1 ? ulm : dlm;
  const float* ph = seg == 0 ? gph : seg == 1 ? uph : dph;
  float2 lm2 = *(const float2*)&lm[id0];
  float2 ph2 = *(const float2*)&ph[id0];
  float m0 = __expf(lm2.x), m1 = __expf(lm2.y);
  float s0, c0, s1, c1;
  __sincosf(ph2.x, &s0, &c0);
  __sincosf(ph2.y, &s1, &c1);
  float wr0 = m0 * c0, wi0 = m0 * s0;
  float wr1 = m1 * c1, wi1 = m1 * s1;
  if (seg < 2) {
    int T = id0 >> 9, k = id0 & 511;
    size_t base = (size_t)(T >> 4) * 64 + (T & 15);
    size_t rR = base + (seg * 2 + 0) * 16;
    size_t rI = base + (seg * 2 + 1) * 16;
    *(unsigned int*)&Wgu[rR * 1024 + k] = pack2(f2bf(wr0), f2bf(wr1));
    *(unsigned int*)&Wgu[rR * 1024 + 512 + k] = pack2(f2bf(-wi0), f2bf(-wi1));
    *(unsigned int*)&Wgu[rI * 1024 + k] = pack2(f2bf(wi0), f2bf(wi1));
    *(unsigned int*)&Wgu[rI * 1024 + 512 + k] = pack2(f2bf(wr0), f2bf(wr1));
  } else {
    int m = id0 >> 11, j = id0 & 2047;
    ushort4 a;
    a.x = f2bf(wr0); a.y = f2bf(-wi0); a.z = f2bf(wr1); a.w = f2bf(-wi1);
    *(ushort4*)&Wd[(size_t)m * 4096 + 2 * j] = a;
    ushort4 b;
    b.x = f2bf(wi0); b.y = f2bf(wr0); b.z = f2bf(wi1); b.w = f2bf(wr1);
    *(ushort4*)&Wd[(size_t)(512 + m) * 4096 + 2 * j] = b;
  }
}

// ---------------------------------------------------------------------------
// Complex LayerNorm (LN2): one WAVE per token. fp32 in -> bf16 (N,1024).
// ---------------------------------------------------------------------------
__global__ __launch_bounds__(256) void cln_kernel(
    const float* __restrict__ xr, const float* __restrict__ xi, int stride,
    const float* __restrict__ g_r, const float* __restrict__ g_i,
    const float* __restrict__ b_r, const float* __restrict__ b_i,
    unsigned short* __restrict__ out) {
  int w = threadIdx.x >> 6, lane = threadIdx.x & 63;
  int t = blockIdx.x * 4 + w;
  int d0 = lane * 8;
  const float* xrt = xr + (size_t)t * stride + d0;
  const float* xit = xi + (size_t)t * stride + d0;
  float4 a0 = *(const float4*)&xrt[0];
  float4 a1 = *(const float4*)&xrt[4];
  float4 c0 = *(const float4*)&xit[0];
  float4 c1 = *(const float4*)&xit[4];

  float s1 = a0.x + a0.y + a0.z + a0.w + a1.x + a1.y + a1.z + a1.w;
  float s2 = c0.x + c0.y + c0.z + c0.w + c1.x + c1.y + c1.z + c1.w;
#pragma unroll
  for (int off = 1; off < 64; off <<= 1) {
    s1 += __shfl_xor(s1, off);
    s2 += __shfl_xor(s2, off);
  }
  float mr = s1 * (1.f / kD), mi = s2 * (1.f / kD);

  float ar[8] = {a0.x, a0.y, a0.z, a0.w, a1.x, a1.y, a1.z, a1.w};
  float ai[8] = {c0.x, c0.y, c0.z, c0.w, c1.x, c1.y, c1.z, c1.w};
  float v = 0.f;
#pragma unroll
  for (int e = 0; e < 8; e++) {
    float cr = ar[e] - mr, ci = ai[e] - mi;
    v += cr * cr + ci * ci;
  }
#pragma unroll
  for (int off = 1; off < 64; off <<= 1) v += __shfl_xor(v, off);
  float inv = rsqrtf(v * (1.f / kD) + 1e-6f);

  unsigned short pr[8], pi[8];
#pragma unroll
  for (int e = 0; e < 8; e++) {
    float nr = (ar[e] - mr) * inv;
    float ni = (ai[e] - mi) * inv;
    pr[e] = f2bf(nr * g_r[d0 + e] - ni * g_i[d0 + e] + b_r[d0 + e]);
    pi[e] = f2bf(nr * g_i[d0 + e] + ni * g_r[d0 + e] + b_i[d0 + e]);
  }
  unsigned short* ot = out + (size_t)t * 1024 + d0;
  *(bf16x8*)&ot[0] = *(const bf16x8*)pr;
  *(bf16x8*)&ot[512] = *(const bf16x8*)pi;
}

// ---------------------------------------------------------------------------
// bf16 MFMA GEMM, 128x128 tile, 4 waves. BK=64 counted-vmcnt double buffer
// (proven skeleton): issue next tile's 8 global_load_lds, vmcnt(8) waits
// only for the PREVIOUS tile's loads; raw barriers. LDS 64 KB dbuf.
// Epilogue modes: 3 = QKV (rope fused, V transposed).
// ---------------------------------------------------------------------------
__global__ __launch_bounds__(256) void cgemm_mfma_kernel(
    const unsigned short* __restrict__ X, int ldx,
    const unsigned short* __restrict__ Wt, int K,
    const float* __restrict__ bias, int mode,
    unsigned short* __restrict__ outb, int ldo,
    unsigned short* __restrict__ vtb) {
  __shared__ unsigned short Sh[32768];  // 64 KB: dbuf x {Xs 8192 | Ws 8192}

  const int tid = threadIdx.x;
  const int w = tid >> 6;
  const int lane = tid & 63;
  const int quad = lane >> 4;
  const int l15 = lane & 15;
  const int m0 = blockIdx.x * 128;
  const int n0 = blockIdx.y * 128;
  const int wm = (w & 1) * 64;
  const int wn = (w >> 1) * 64;

  const int rsub = lane >> 3;                    // 0..7
  const int grow = w * 32 + rsub;                // + t*8 per inst
  const int gcol = ((lane & 7) ^ rsub) * 8;      // swizzled global granule
  const unsigned short* gx = X + (size_t)(n0 + grow) * ldx + gcol;
  const unsigned short* gw = Wt + (size_t)(m0 + grow) * K + gcol;

  const int rg = (l15 & 7);                      // read-side swizzle key

  f32x4 acc[4][4];
#pragma unroll
  for (int i = 0; i < 4; i++)
#pragma unroll
    for (int j = 0; j < 4; j++) acc[i][j] = (f32x4){0.f, 0.f, 0.f, 0.f};

  auto stage_tile = [&](int kt, int bsel) {
    const int k0 = kt * 64;
    unsigned short* dX = &Sh[bsel * 16384 + w * 2048];
    unsigned short* dW = &Sh[bsel * 16384 + 8192 + w * 2048];
#pragma unroll
    for (int t = 0; t < 4; t++) {
      __builtin_amdgcn_global_load_lds((const AS1 void*)(gx + (size_t)t * 8 * ldx + k0),
                                       (AS3 void*)(dX + t * 512), 16, 0, 0);
      __builtin_amdgcn_global_load_lds((const AS1 void*)(gw + (size_t)t * 8 * K + k0),
                                       (AS3 void*)(dW + t * 512), 16, 0, 0);
    }
  };

  const int nt = K >> 6;
  stage_tile(0, 0);
  for (int t = 0; t < nt; ++t) {
    if (t + 1 < nt) {
      stage_tile(t + 1, (t + 1) & 1);
      asm volatile("s_waitcnt vmcnt(8)" ::: "memory");
    } else {
      asm volatile("s_waitcnt vmcnt(0)" ::: "memory");
    }
    BARC();  // tile t's loads complete & visible
    const unsigned short* Xs = &Sh[(t & 1) * 16384];
    const unsigned short* Ws = &Sh[(t & 1) * 16384 + 8192];
#pragma unroll
    for (int ks = 0; ks < 2; ks++) {
      const int gsel = ((ks * 4 + quad) ^ rg) * 8;
      bf16x8 af[4], bf[4];
#pragma unroll
      for (int t2 = 0; t2 < 4; t2++) {
        af[t2] = *(const bf16x8*)&Xs[(wn + t2 * 16 + l15) * 64 + gsel];
        bf[t2] = *(const bf16x8*)&Ws[(wm + t2 * 16 + l15) * 64 + gsel];
      }
#pragma unroll
      for (int i = 0; i < 4; i++)
#pragma unroll
        for (int j = 0; j < 4; j++)
          acc[i][j] = __builtin_amdgcn_mfma_f32_16x16x32_bf16(af[i], bf[j], acc[i][j], 0, 0, 0);
    }
    BARC();  // protect buf (t+1)&1 from restage before all reads done
  }

  // ---- epilogue; D mapping: col=lane&15 (feature), row=(lane>>4)*4+reg ----
  if (mode == 3 && m0 < 2048) {
    // q/k: bias + fused RoPE (angle-addition)
#pragma unroll
    for (int j = 0; j < 4; ++j) {
      float bv = bias[m0 + wm + j * 16 + l15];
#pragma unroll
      for (int i = 0; i < 4; ++i)
#pragma unroll
        for (int r = 0; r < 4; ++r) acc[i][j][r] += bv;
    }
    const int sbase = ((n0 + wn) & (kS - 1)) + quad * 4;
#pragma unroll
    for (int j01 = 0; j01 < 2; ++j01) {
      float fi = (float)(j01 * 16 + l15);
      float f = __expf(fi * -0.28782313662425572f);  // -ln(10000)/32
      float c1, s1, c16, s16, cI, sI;
      __sincosf(f, &s1, &c1);
      __sincosf(16.f * f, &s16, &c16);
      __sincosf((float)sbase * f, &sI, &cI);
#pragma unroll
      for (int i = 0; i < 4; ++i) {
        float cc = cI, ss = sI;
#pragma unroll
        for (int r = 0; r < 4; ++r) {
          float x0 = acc[i][j01][r], x1 = acc[i][j01 + 2][r];
          acc[i][j01][r] = x0 * cc - x1 * ss;
          acc[i][j01 + 2][r] = x1 * cc + x0 * ss;
          float cn = cc * c1 - ss * s1;
          ss = ss * c1 + cc * s1;
          cc = cn;
        }
        float cn = cI * c16 - sI * s16;
        sI = sI * c16 + cI * s16;
        cI = cn;
      }
    }
#pragma unroll
    for (int j = 0; j < 4; ++j) {
      int col = m0 + wm + j * 16 + l15;
#pragma unroll
      for (int i = 0; i < 4; ++i) {
        int row0 = n0 + wn + i * 16 + quad * 4;
#pragma unroll
        for (int r = 0; r < 4; ++r)
          outb[(size_t)(row0 + r) * ldo + col] = f2bf(acc[i][j][r]);
      }
    }
  } else {
    // V: LDS-staged transpose, two wave-parity passes. Ts = 64 x 130 shorts.
    unsigned short* Ts = Sh;
#pragma unroll
    for (int p = 0; p < 2; ++p) {
      __syncthreads();
      if ((w & 1) == p) {
#pragma unroll
        for (int j = 0; j < 4; ++j) {
          float bv = bias[m0 + wm + j * 16 + l15];
          int fl = j * 16 + l15;
#pragma unroll
          for (int i = 0; i < 4; ++i) {
            int tk = wn + i * 16 + quad * 4;
#pragma unroll
            for (int r = 0; r < 4; ++r)
              Ts[fl * 130 + tk + r] = f2bf(acc[i][j][r] + bv);
          }
        }
      }
      __syncthreads();
      {
        int fr = tid >> 2, seg = tid & 3;
        int f = (m0 - 2048) + p * 64 + fr;
        int hh = f >> 7, dc = f & 127;
        int bb = n0 >> 10, sbase2 = (n0 & (kS - 1)) + seg * 32;
        unsigned short* dst = &vtb[(size_t)((bb * 8 + hh) * 128 + dc) * 1024 + sbase2];
        const unsigned short* src = &Ts[fr * 130 + seg * 32];
#pragma unroll
        for (int u = 0; u < 4; u++)
          *(bf16x8*)(dst + u * 8) = *(const bf16x8*)(src + u * 8);
      }
    }
  }
}

// ---------------------------------------------------------------------------
// 256x256-tile bf16 MFMA GEMM for gate+up (mode-4 epilogue fused).
// R4 version (best measured): 8-phase schedule, 8 waves, chunk-granular
// staging, counted vmcnt(4), setprio around MFMA quadrants.
// ---------------------------------------------------------------------------
__global__ __launch_bounds__(512, 2) void cgemm_mfma_gu256_kernel(
    const unsigned short* __restrict__ X, int ldx,
    const unsigned short* __restrict__ Wt, int K,
    unsigned short* __restrict__ outb, int ldo) {
  __shared__ unsigned short Sh[65536];  // 128 KiB: per buf {X 256x64 | W 256x64}

  const int tid = threadIdx.x;
  const int w = tid >> 6;           // 0..7
  const int lane = tid & 63;
  const int quad = lane >> 4;
  const int l15 = lane & 15;
  const int m0 = blockIdx.x * 256;  // features
  const int n0 = blockIdx.y * 256;  // tokens
  const int wfeat = w & 1;          // feature half (128 wide)
  const int wtok = w >> 1;          // token quarter (64 wide)
  const int swz = l15 & 7;          // read-side swizzle key (= row & 7)

  const int srow = lane >> 3;                     // 0..7
  const int sgran = ((lane & 7) ^ srow) * 8;      // pre-swizzled global granule

  f32x4 acc[4][8];
#pragma unroll
  for (int i = 0; i < 4; i++)
#pragma unroll
    for (int j = 0; j < 8; j++) acc[i][j] = (f32x4){0.f, 0.f, 0.f, 0.f};

  // chunk: 0=X-lo, 1=X-hi, 2=W-lo, 3=W-hi (128 rows x 64 cols, 2 loads/thread)
  auto stage_chunk = [&](int kt, int which) {
    const int k0 = kt * 64;
    const int bsel = kt & 1;
    const int half = which & 1;
    if (which < 2) {
      const unsigned short* g =
          X + (size_t)(n0 + half * 128 + w * 16 + srow) * ldx + k0 + sgran;
      unsigned short* d = &Sh[bsel * 32768 + (half * 128 + w * 16) * 64];
#pragma unroll
      for (int u = 0; u < 2; ++u)
        __builtin_amdgcn_global_load_lds((const AS1 void*)(g + (size_t)u * 8 * ldx),
                                         (AS3 void*)(d + u * 512), 16, 0, 0);
    } else {
      const unsigned short* g =
          Wt + (size_t)(m0 + half * 128 + w * 16 + srow) * K + k0 + sgran;
      unsigned short* d = &Sh[bsel * 32768 + 16384 + (half * 128 + w * 16) * 64];
#pragma unroll
      for (int u = 0; u < 2; ++u)
        __builtin_amdgcn_global_load_lds((const AS1 void*)(g + (size_t)u * 8 * K),
                                         (AS3 void*)(d + u * 512), 16, 0, 0);
    }
  };

  bf16x8 af[4][2];
  bf16x8 bq[4];

  auto read_bq = [&](const unsigned short* Bs, int ks, int jh) {
#pragma unroll
    for (int jj = 0; jj < 4; ++jj)
      bq[jj] = *(const bf16x8*)&Bs[(wfeat * 128 + jh * 64 + jj * 16 + l15) * 64 +
                                   (((ks * 4 + quad) ^ swz) * 8)];
  };

  auto mfma_quad = [&](int ks, int jh) {
    __builtin_amdgcn_s_barrier();
    __builtin_amdgcn_s_setprio(1);
#pragma unroll
    for (int i = 0; i < 4; ++i)
#pragma unroll
      for (int jj = 0; jj < 4; ++jj)
        acc[i][jh * 4 + jj] = __builtin_amdgcn_mfma_f32_16x16x32_bf16(
            af[i][ks], bq[jj], acc[i][jh * 4 + jj], 0, 0, 0);
    __builtin_amdgcn_s_setprio(0);
    __builtin_amdgcn_s_barrier();
  };

  const int nt = K >> 6;  // 16
  // prologue: tile0 all 4 chunks + tile1 X chunks; wait tile0 landed
  stage_chunk(0, 0); stage_chunk(0, 1); stage_chunk(0, 2); stage_chunk(0, 3);
  stage_chunk(1, 0); stage_chunk(1, 1);
  asm volatile("s_waitcnt vmcnt(4)" ::: "memory");
  __builtin_amdgcn_s_barrier();

  for (int t = 0; t < nt; ++t) {
    const unsigned short* As = &Sh[(t & 1) * 32768];
    const unsigned short* Bs = &Sh[(t & 1) * 32768 + 16384];

    // ---- p0: (ks0, jh0); read ALL af ----
#pragma unroll
    for (int i = 0; i < 4; ++i)
#pragma unroll
      for (int ks = 0; ks < 2; ++ks)
        af[i][ks] = *(const bf16x8*)&As[(wtok * 64 + i * 16 + l15) * 64 +
                                        (((ks * 4 + quad) ^ swz) * 8)];
    read_bq(Bs, 0, 0);
    if (t + 1 < nt) stage_chunk(t + 1, 2);
    mfma_quad(0, 0);
#pragma unroll
    for (int i = 0; i < 4; ++i) asm volatile("" :: "v"(af[i][1]));

    // ---- p1: (ks0, jh1) ----
    read_bq(Bs, 0, 1);
    if (t + 1 < nt) stage_chunk(t + 1, 3);
    mfma_quad(0, 1);

    // ---- p2: (ks1, jh0) ----
    read_bq(Bs, 1, 0);
    if (t + 2 < nt) stage_chunk(t + 2, 0);
    mfma_quad(1, 0);

    // ---- p3: (ks1, jh1) ----
    read_bq(Bs, 1, 1);
    if (t + 2 < nt) {
      stage_chunk(t + 2, 1);
      asm volatile("s_waitcnt vmcnt(4)" ::: "memory");
    } else {
      asm volatile("s_waitcnt vmcnt(0)" ::: "memory");
    }
    mfma_quad(1, 1);
  }

  // ---- gating epilogue; role-in-j: j=0..3 role group jh=0, j=4..7 jh=1 ----
#pragma unroll
  for (int i = 0; i < 4; ++i) {
    int row0 = n0 + wtok * 64 + i * 16 + quad * 4;
#pragma unroll
    for (int jh = 0; jh < 2; ++jh) {
      int T = ((m0 + wfeat * 128 + jh * 64) >> 6) * 16 + l15;
#pragma unroll
      for (int r = 0; r < 4; ++r) {
        float gr = acc[i][jh * 4 + 0][r], gi = acc[i][jh * 4 + 1][r];
        float ur = acc[i][jh * 4 + 2][r], ui = acc[i][jh * 4 + 3][r];
        float sg = __builtin_amdgcn_rcpf(1.f + __expf(-sqrtf(gr * gr + gi * gi)));
        float gar = gr * sg, gai = gi * sg;
        unsigned int pk = pack2(f2bf(gar * ur - gai * ui), f2bf(gar * ui + gai * ur));
        *(unsigned int*)&outb[(size_t)(row0 + r) * ldo + 2 * T] = pk;
      }
    }
  }
}

// ---------------------------------------------------------------------------
// bf16 MFMA GEMM, 64x128 tile, 4 waves. BK=64 counted-vmcnt double buffer.
// R7: separate ldw (W row stride) from K (loop bound) + optional K-split via
// blockIdx.z (mode 2): split z processes K-slice [z*K, (z+1)*K); epilogue
// becomes atomicAdd onto zeroed outf (split 0 folds the residual in).
// fp32 epilogues: 1 = O-proj (+bias +x residual, plain store),
//                 2 = down K-split partial (atomicAdd -> d_out).
// ---------------------------------------------------------------------------
__global__ __launch_bounds__(256) void cgemm_mfma_n64_kernel(
    const unsigned short* __restrict__ X, int ldx,
    const unsigned short* __restrict__ Wt, int K, int ldw,
    const float* __restrict__ bias, int mode,
    const float* __restrict__ resr, const float* __restrict__ resi,
    float* __restrict__ outf) {
  __shared__ unsigned short Sh[24576];  // 48 KB: {X0|W0|X1|W1}, 12288 shorts/buf

  const int tid = threadIdx.x;
  const int w = tid >> 6;
  const int lane = tid & 63;
  const int quad = lane >> 4;
  const int l15 = lane & 15;
  const int m0 = blockIdx.x * 128;
  const int n0 = blockIdx.y * 64;
  const int wm = (w & 1) * 64;
  const int wn = (w >> 1) * 32;
  const int swz = l15 & 7;

  const int ksplit = (mode == 2) ? blockIdx.z : 0;
  const unsigned short* Xb = X + (size_t)ksplit * K;
  const unsigned short* Wb = Wt + (size_t)ksplit * K;
  const float* resp = (ksplit == 0) ? resr : nullptr;

  // staging: per gload a wave covers 8 rows x 8 granules (swizzled source)
  const int srow = lane >> 3;
  const int sgran = ((lane & 7) ^ srow) * 8;
  const unsigned short* gX = Xb + (size_t)(n0 + w * 16 + srow) * ldx + sgran;
  const unsigned short* gW = Wb + (size_t)(m0 + w * 32 + srow) * ldw + sgran;

  f32x4 acc[2][4];
#pragma unroll
  for (int i = 0; i < 2; i++)
#pragma unroll
    for (int j = 0; j < 4; j++) acc[i][j] = (f32x4){0.f, 0.f, 0.f, 0.f};

  auto stage_tile = [&](int kt, int bsel) {
    const int k0 = kt * 64;
    unsigned short* dX = &Sh[bsel * 12288 + w * 1024];         // 16 rows/wave
    unsigned short* dW = &Sh[bsel * 12288 + 4096 + w * 2048];  // 32 rows/wave
#pragma unroll
    for (int u = 0; u < 2; ++u)
      __builtin_amdgcn_global_load_lds((const AS1 void*)(gX + (size_t)u * 8 * ldx + k0),
                                       (AS3 void*)(dX + u * 512), 16, 0, 0);
#pragma unroll
    for (int u = 0; u < 4; ++u)
      __builtin_amdgcn_global_load_lds((const AS1 void*)(gW + (size_t)u * 8 * ldw + k0),
                                       (AS3 void*)(dW + u * 512), 16, 0, 0);
  };

  const int nt = K >> 6;
  stage_tile(0, 0);
  for (int t = 0; t < nt; ++t) {
    if (t + 1 < nt) {
      stage_tile(t + 1, (t + 1) & 1);
      asm volatile("s_waitcnt vmcnt(6)" ::: "memory");
    } else {
      asm volatile("s_waitcnt vmcnt(0)" ::: "memory");
    }
    BARC();  // tile t's loads complete & visible
    const unsigned short* Xs = &Sh[(t & 1) * 12288];
    const unsigned short* Ws = &Sh[(t & 1) * 12288 + 4096];
#pragma unroll
    for (int ks = 0; ks < 2; ++ks) {
      const int gsel = ((ks * 4 + quad) ^ swz) * 8;
      bf16x8 af[2], bf[4];
#pragma unroll
      for (int t2 = 0; t2 < 2; ++t2)
        af[t2] = *(const bf16x8*)&Xs[(wn + t2 * 16 + l15) * 64 + gsel];
#pragma unroll
      for (int t2 = 0; t2 < 4; ++t2)
        bf[t2] = *(const bf16x8*)&Ws[(wm + t2 * 16 + l15) * 64 + gsel];
#pragma unroll
      for (int i = 0; i < 2; i++)
#pragma unroll
        for (int j = 0; j < 4; j++)
          acc[i][j] = __builtin_amdgcn_mfma_f32_16x16x32_bf16(af[i], bf[j], acc[i][j], 0, 0, 0);
    }
    BARC();  // protect buf (t+1)&1 from being restaged before all reads done
  }

#pragma unroll
  for (int j = 0; j < 4; ++j) {
    int col = m0 + wm + j * 16 + l15;
    float bv = bias ? bias[col] : 0.f;
#pragma unroll
    for (int i = 0; i < 2; ++i) {
      int row0 = n0 + wn + i * 16 + quad * 4;
#pragma unroll
      for (int r = 0; r < 4; ++r) {
        int row = row0 + r;
        float val = acc[i][j][r] + bv;
        if (mode == 1) {
          float xres = (col < 512) ? resr[(size_t)row * 512 + col]
                                   : resi[(size_t)row * 512 + col - 512];
          outf[(size_t)row * 1024 + col] = val + xres;
        } else {
          float rv = val + (resp ? resp[(size_t)row * 1024 + col] : 0.f);
          size_t dd = (col < 512) ? ((size_t)row * 512 + col)
                                  : ((size_t)kBSD + (size_t)row * 512 + (col - 512));
          atomicAdd(&outf[dd], rv);
        }
      }
    }
  }
}

// ---------------------------------------------------------------------------
// MFMA flash attention (causal, Hermitian). K-tile = 64.
// T14 async-STAGE split: K/V tile kt+1 prefetched into 32 registers before
// compute of tile kt; reg->LDS writes at top of next iteration (raw barrier
// + explicit lgkmcnt(0) so the in-flight global loads are not drained).
// LDS: Ks 64x136 + Vs 128x72 + Ps 4x16x72 = 45,056 B.
// ---------------------------------------------------------------------------
__global__ __launch_bounds__(256) void attn_mfma_kernel(
    const unsigned short* __restrict__ qkv,   // (4096, 3072)
    const unsigned short* __restrict__ vt,    // (4,8,128,1024)
    unsigned short* __restrict__ out) {       // (4096, 1024) [ar|ai]
  __shared__ unsigned short Ks[64 * 136];
  __shared__ unsigned short Vs[128 * 72];
  __shared__ unsigned short Ps[4 * 16 * 72];

  const int tid = threadIdx.x;
  const int w = tid >> 6;
  const int lane = tid & 63;
  const int quad = lane >> 4;
  const int l15 = lane & 15;

  int bid = blockIdx.x;
  int second = bid >> 8;             // 0: blocks 0..255, 1: 256..511
  int u = bid & 255;
  int t_ = u & 15;
  const int qt = second ? (15 - t_) : t_;   // complementary across halves
  const int h = (u >> 4) & 7;
  const int b = second * 2 + (u >> 7);
  const int q0 = qt * 64;
  const int wrow0 = q0 + w * 16;

  bf16x8 qa[4];
  {
    size_t base = (size_t)(b * kS + wrow0 + l15) * 3072 + h * 128;
#pragma unroll
    for (int ks = 0; ks < 4; ks++)
      qa[ks] = *(const bf16x8*)&qkv[base + ks * 32 + quad * 8];
  }

  f32x4 oacc[8];
#pragma unroll
  for (int dt = 0; dt < 8; dt++) oacc[dt] = (f32x4){0.f, 0.f, 0.f, 0.f};
  float m_r[4] = {-1e30f, -1e30f, -1e30f, -1e30f};
  float l_r[4] = {0.f, 0.f, 0.f, 0.f};

  const int nkt = qt + 1;
  const float cexp = 0.1803368801f;  // (1/sqrt(64)) * log2(e)

  const unsigned short* gkbase = qkv + 1024 + h * 128;
  const unsigned short* gvbase = vt + (size_t)((b * 8 + h) * 128) * 1024;

  const int ch = tid * 4;
  bf16x8 kreg[4], vreg[4];
  auto load_kv = [&](int k0) {
    const unsigned short* gk = gkbase + (size_t)(b * kS + k0) * 3072;
#pragma unroll
    for (int u2 = 0; u2 < 4; u2++) {
      int idx = ch + u2, r = idx >> 4, cc = (idx & 15) * 8;
      kreg[u2] = *(const bf16x8*)&gk[(size_t)r * 3072 + cc];
    }
#pragma unroll
    for (int u2 = 0; u2 < 4; u2++) {
      int idx = ch + u2, vr = idx >> 3, vc = (idx & 7) * 8;
      vreg[u2] = *(const bf16x8*)&gvbase[(size_t)vr * 1024 + k0 + vc];
    }
  };

  load_kv(0);

  for (int kt = 0; kt < nkt; ++kt) {
    const int k0 = kt * 64;
    BARC();  // all waves done reading Ks/Vs from the previous tile
    // write the prefetched tile to LDS (compiler inserts the vmcnt waits
    // for kreg/vreg defs right here — exactly where they are needed)
#pragma unroll
    for (int u2 = 0; u2 < 4; u2++) {
      int idx = ch + u2, r = idx >> 4, cc = (idx & 15) * 8;
      *(bf16x8*)&Ks[r * 136 + cc] = kreg[u2];
    }
#pragma unroll
    for (int u2 = 0; u2 < 4; u2++) {
      int idx = ch + u2, vr = idx >> 3, vc = (idx & 7) * 8;
      *(bf16x8*)&Vs[vr * 72 + vc] = vreg[u2];
    }
    // kick next tile's global loads — they fly during compute below
    if (kt + 1 < nkt) load_kv(k0 + 64);
    asm volatile("s_waitcnt lgkmcnt(0)" ::: "memory");  // ds_writes complete
    BARC();  // Ks/Vs visible to all waves; prefetch NOT drained

    f32x4 s[4];
#pragma unroll
    for (int ns = 0; ns < 4; ns++) {
      s[ns] = (f32x4){0.f, 0.f, 0.f, 0.f};
#pragma unroll
      for (int ks = 0; ks < 4; ks++) {
        bf16x8 kb = *(const bf16x8*)&Ks[(ns * 16 + l15) * 136 + ks * 32 + quad * 8];
        s[ns] = __builtin_amdgcn_mfma_f32_16x16x32_bf16(qa[ks], kb, s[ns], 0, 0, 0);
      }
    }

    if (k0 + 63 > wrow0) {
#pragma unroll
      for (int r = 0; r < 4; r++) {
        int qrow = wrow0 + quad * 4 + r;
#pragma unroll
        for (int ns = 0; ns < 4; ns++)
          if (k0 + ns * 16 + l15 > qrow) s[ns][r] = -1e30f;
      }
    }

    float alpha[4];
#pragma unroll
    for (int r = 0; r < 4; r++) {
      float mx = fmaxf(fmaxf(s[0][r], s[1][r]), fmaxf(s[2][r], s[3][r]));
      mx = fmaxf(mx, __shfl_xor(mx, 1));
      mx = fmaxf(mx, __shfl_xor(mx, 2));
      mx = fmaxf(mx, __shfl_xor(mx, 4));
      mx = fmaxf(mx, __shfl_xor(mx, 8));
      float mn = fmaxf(m_r[r], mx);
      float al = exp2f((m_r[r] - mn) * cexp);
      m_r[r] = mn;
      float rs = 0.f;
#pragma unroll
      for (int ns = 0; ns < 4; ns++) {
        float p = exp2f((s[ns][r] - mn) * cexp);
        s[ns][r] = p;
        rs += p;
      }
      rs += __shfl_xor(rs, 1);
      rs += __shfl_xor(rs, 2);
      rs += __shfl_xor(rs, 4);
      rs += __shfl_xor(rs, 8);
      l_r[r] = l_r[r] * al + rs;
      alpha[r] = al;
    }

#pragma unroll
    for (int dt = 0; dt < 8; dt++)
#pragma unroll
      for (int r = 0; r < 4; r++) oacc[dt][r] *= alpha[r];

    unsigned short* pw = &Ps[w * 1152];
#pragma unroll
    for (int r = 0; r < 4; r++) {
      int q = quad * 4 + r;
#pragma unroll
      for (int ns = 0; ns < 4; ns++)
        pw[q * 72 + ns * 16 + l15] = f2bf(s[ns][r]);
    }
    bf16x8 pa0 = *(const bf16x8*)&pw[l15 * 72 + quad * 8];
    bf16x8 pa1 = *(const bf16x8*)&pw[l15 * 72 + 32 + quad * 8];

#pragma unroll
    for (int dt = 0; dt < 8; dt++) {
      bf16x8 vb0 = *(const bf16x8*)&Vs[(dt * 16 + l15) * 72 + quad * 8];
      bf16x8 vb1 = *(const bf16x8*)&Vs[(dt * 16 + l15) * 72 + 32 + quad * 8];
      oacc[dt] = __builtin_amdgcn_mfma_f32_16x16x32_bf16(pa0, vb0, oacc[dt], 0, 0, 0);
      oacc[dt] = __builtin_amdgcn_mfma_f32_16x16x32_bf16(pa1, vb1, oacc[dt], 0, 0, 0);
    }
  }

  float inv[4];
#pragma unroll
  for (int r = 0; r < 4; r++) inv[r] = __builtin_amdgcn_rcpf(l_r[r]);
#pragma unroll
  for (int dt = 0; dt < 8; dt++) {
    int dcat = dt * 16 + l15;
    int col = (dcat < 64) ? (h * 64 + dcat) : (512 + h * 64 + dcat - 64);
#pragma unroll
    for (int r = 0; r < 4; r++) {
      int tok = b * kS + wrow0 + quad * 4 + r;
      out[(size_t)tok * 1024 + col] = f2bf(oacc[dt][r] * inv[r]);
    }
  }
}

// ---------------------------------------------------------------------------
// Launcher
// ---------------------------------------------------------------------------
extern "C" void kernel_launch(void* const* d_in, const int* in_sizes, int n_in,
                              void* d_out, int out_size, void* d_ws, size_t ws_size,
                              hipStream_t stream) {
  const float* x_real = (const float*)d_in[0];
  const float* x_imag = (const float*)d_in[1];
  const float* ln1_gr = (const float*)d_in[2];
  const float* ln1_gi = (const float*)d_in[3];
  const float* ln1_br = (const float*)d_in[4];
  const float* ln1_bi = (const float*)d_in[5];
  const float* q_lm = (const float*)d_in[6];
  const float* q_ph = (const float*)d_in[7];
  const float* q_bm = (const float*)d_in[8];
  const float* q_bp = (const float*)d_in[9];
  const float* k_lm = (const float*)d_in[10];
  const float* k_ph = (const float*)d_in[11];
  const float* k_bm = (const float*)d_in[12];
  const float* k_bp = (const float*)d_in[13];
  const float* v_lm = (const float*)d_in[14];
  const float* v_ph = (const float*)d_in[15];
  const float* v_bm = (const float*)d_in[16];
  const float* v_bp = (const float*)d_in[17];
  const float* o_lm = (const float*)d_in[18];
  const float* o_ph = (const float*)d_in[19];
  const float* o_bm = (const float*)d_in[20];
  const float* o_bp = (const float*)d_in[21];
  const float* ln2_gr = (const float*)d_in[22];
  const float* ln2_gi = (const float*)d_in[23];
  const float* ln2_br = (const float*)d_in[24];
  const float* ln2_bi = (const float*)d_in[25];
  const float* gate_lm = (const float*)d_in[26];
  const float* gate_ph = (const float*)d_in[27];
  const float* up_lm = (const float*)d_in[28];
  const float* up_ph = (const float*)d_in[29];
  const float* down_lm = (const float*)d_in[30];
  const float* down_ph = (const float*)d_in[31];

  // ---- workspace layout (bytes) ----
  char* wsb = (char*)d_ws;
  unsigned short* Wqkv = (unsigned short*)(wsb + 0);           // 3072x1024 bf16
  unsigned short* Wo   = (unsigned short*)(wsb + 6291456);     // 1024x1024
  unsigned short* Wgu  = (unsigned short*)(wsb + 8388608);     // 8192x1024 (role-in-j)
  unsigned short* Wd   = (unsigned short*)(wsb + 25165824);    // 1024x4096 (interleaved K)
  float* qkvBias = (float*)(wsb + 33554432);                   // 3072 fp32
  float* oBias   = (float*)(wsb + 33566720);                   // 1024 fp32
  float* res     = (float*)(wsb + 33570816);                   // 4096x1024 fp32
  unsigned short* H = (unsigned short*)(wsb + 50348032);       // 4096x1024 bf16
  char* big = wsb + 58736640;
  unsigned short* qkv     = (unsigned short*)big;              // 4096x3072 bf16
  unsigned short* attnout = (unsigned short*)(big + 25165824); // 4096x1024 bf16
  unsigned short* vtb     = (unsigned short*)(big + 33554432); // 4x8x128x1024 bf16
  unsigned short* hid     = (unsigned short*)big;              // 4096x4096 bf16 (aliases dead bufs)

  float* outf = (float*)d_out;  // (2, 4096, 512)

  // 0) zero d_out for the down GEMM's K-split atomic accumulation
  hipMemsetAsync(d_out, 0, out_size, stream);

  // 1) fused builds (wA includes biases + LN1)
  build_wA_kernel<<<5128, 256, 0, stream>>>(q_lm, q_ph, k_lm, k_ph, v_lm, v_ph,
                                            o_lm, o_ph, q_bm, q_bp, k_bm, k_bp,
                                            v_bm, v_bp, o_bm, o_bp,
                                            x_real, x_imag, ln1_gr, ln1_gi,
                                            ln1_br, ln1_bi,
                                            Wqkv, Wo, qkvBias, oBias, H);
  build_wB_kernel<<<6144, 256, 0, stream>>>(gate_lm, gate_ph, up_lm, up_ph,
                                            down_lm, down_ph, Wgu, Wd);

  // 2) QKV fused GEMM (mode 3, counted-vmcnt dbuf): rope fused, V -> vtb
  {
    dim3 g(3072 / 128, kNT / 128);
    cgemm_mfma_kernel<<<g, 256, 0, stream>>>(H, 1024, Wqkv, 1024, qkvBias, 3, qkv, 3072, vtb);
  }

  // 3) attention -> attnout (load-balanced decode, T14 K/V prefetch)
  attn_mfma_kernel<<<kB * kH * (kS / 64), 256, 0, stream>>>(qkv, vtb, attnout);

  // 4) O-proj + x residual -> res fp32 (BK=64 counted-vmcnt dbuf)
  {
    dim3 g(1024 / 128, kNT / 64);
    cgemm_mfma_n64_kernel<<<g, 256, 0, stream>>>(attnout, 1024, Wo, 1024, 1024, oBias, 1,
                                                 x_real, x_imag, res);
  }

  // 5) LN2: res -> H
  cln_kernel<<<kNT / 4, 256, 0, stream>>>(res, res + 512, 1024, ln2_gr, ln2_gi, ln2_br, ln2_bi, H);

  // 6) gate+up GEMM, 256^2 8-phase counted-vmcnt schedule (best) -> hid
  {
    dim3 g(8192 / 256, kNT / 256);
    cgemm_mfma_gu256_kernel<<<g, 512, 0, stream>>>(H, 1024, Wgu, 1024, hid, 4096);
  }

  // 7) down GEMM, K-split x2 in one dispatch (blockIdx.z), atomicAdd + res
  {
    dim3 g(1024 / 128, kNT / 64, 2);
    cgemm_mfma_n64_kernel<<<g, 256, 0, stream>>>(hid, 4096, Wd, 2048, 4096, nullptr, 2,
                                                 res, nullptr, outf);
  }
}

// Round 8
// 365.670 us; speedup vs baseline: 1.1002x; 1.1002x over previous
//
#include <hip/hip_runtime.h>
#include <math.h>

// Problem constants: B=4, S=1024, D=512, H=8, HD=64, HID=2048
#define kB 4
#define kS 1024
#define kD 512
#define kH 8
#define kHD 64
#define kHID 2048
#define kNT (kB * kS)          // 4096 tokens
#define kBSD (kNT * kD)        // 2,097,152

typedef __attribute__((ext_vector_type(8))) short bf16x8;
typedef __attribute__((ext_vector_type(4))) float f32x4;

#define AS1 __attribute__((address_space(1)))
#define AS3 __attribute__((address_space(3)))

__device__ __forceinline__ float bf2f(unsigned short u) {
  return __uint_as_float(((unsigned int)u) << 16);
}
__device__ __forceinline__ unsigned short f2bf(float f) {
  unsigned int u = __float_as_uint(f);
  u += 0x7fffu + ((u >> 16) & 1u);   // RNE
  return (unsigned short)(u >> 16);
}
__device__ __forceinline__ unsigned int pack2(unsigned short a, unsigned short b) {
  return (unsigned)a | ((unsigned)b << 16);
}

#define BARC() do { asm volatile("" ::: "memory"); __builtin_amdgcn_s_barrier(); asm volatile("" ::: "memory"); } while (0)

// ---------------------------------------------------------------------------
// Fused build A: QKV (head-permuted) + O (standard cat) + biases + LN1.
// grid 5128 x 256:
//   blocks [0,4096):    weights, seg = gid>>18: 0=q,1=k,2=v (perm), 3=o (std)
//   blocks [4096,4104): biases (2048 threads over 4 segments)
//   blocks [4104,5128): LN1 (one wave per token, 4 tokens/block)
// ---------------------------------------------------------------------------
__global__ __launch_bounds__(256) void build_wA_kernel(
    const float* __restrict__ qlm, const float* __restrict__ qph,
    const float* __restrict__ klm, const float* __restrict__ kph,
    const float* __restrict__ vlm, const float* __restrict__ vph,
    const float* __restrict__ olm, const float* __restrict__ oph,
    const float* __restrict__ qbm, const float* __restrict__ qbp,
    const float* __restrict__ kbm, const float* __restrict__ kbp,
    const float* __restrict__ vbm, const float* __restrict__ vbp,
    const float* __restrict__ obm, const float* __restrict__ obp,
    const float* __restrict__ xr, const float* __restrict__ xi,
    const float* __restrict__ g_r, const float* __restrict__ g_i,
    const float* __restrict__ b_r, const float* __restrict__ b_i,
    unsigned short* __restrict__ Wqkv, unsigned short* __restrict__ Wo,
    float* __restrict__ qkvBias, float* __restrict__ oBias,
    unsigned short* __restrict__ H) {
  int bx = blockIdx.x;
  if (bx >= 4104) {
    // ---- LN1: one wave per token ----
    int w = threadIdx.x >> 6, lane = threadIdx.x & 63;
    int t = (bx - 4104) * 4 + w;
    int d0 = lane * 8;
    const float* xrt = xr + (size_t)t * 512 + d0;
    const float* xit = xi + (size_t)t * 512 + d0;
    float4 a0 = *(const float4*)&xrt[0];
    float4 a1 = *(const float4*)&xrt[4];
    float4 c0 = *(const float4*)&xit[0];
    float4 c1 = *(const float4*)&xit[4];
    float s1 = a0.x + a0.y + a0.z + a0.w + a1.x + a1.y + a1.z + a1.w;
    float s2 = c0.x + c0.y + c0.z + c0.w + c1.x + c1.y + c1.z + c1.w;
#pragma unroll
    for (int off = 1; off < 64; off <<= 1) {
      s1 += __shfl_xor(s1, off);
      s2 += __shfl_xor(s2, off);
    }
    float mr = s1 * (1.f / kD), mi = s2 * (1.f / kD);
    float ar[8] = {a0.x, a0.y, a0.z, a0.w, a1.x, a1.y, a1.z, a1.w};
    float ai[8] = {c0.x, c0.y, c0.z, c0.w, c1.x, c1.y, c1.z, c1.w};
    float v = 0.f;
#pragma unroll
    for (int e = 0; e < 8; e++) {
      float cr = ar[e] - mr, ci = ai[e] - mi;
      v += cr * cr + ci * ci;
    }
#pragma unroll
    for (int off = 1; off < 64; off <<= 1) v += __shfl_xor(v, off);
    float inv = rsqrtf(v * (1.f / kD) + 1e-6f);
    unsigned short pr[8], pi[8];
#pragma unroll
    for (int e = 0; e < 8; e++) {
      float nr = (ar[e] - mr) * inv;
      float ni = (ai[e] - mi) * inv;
      pr[e] = f2bf(nr * g_r[d0 + e] - ni * g_i[d0 + e] + b_r[d0 + e]);
      pi[e] = f2bf(nr * g_i[d0 + e] + ni * g_r[d0 + e] + b_i[d0 + e]);
    }
    unsigned short* ot = H + (size_t)t * 1024 + d0;
    *(bf16x8*)&ot[0] = *(const bf16x8*)pr;
    *(bf16x8*)&ot[512] = *(const bf16x8*)pi;
    return;
  }
  if (bx >= 4096) {
    int gid = (bx - 4096) * 256 + threadIdx.x;  // 0..2047
    int seg = gid >> 9, m = gid & 511;
    const float* bm = seg == 0 ? qbm : seg == 1 ? kbm : seg == 2 ? vbm : obm;
    const float* bp = seg == 0 ? qbp : seg == 1 ? kbp : seg == 2 ? vbp : obp;
    float s, c;
    __sincosf(bp[m], &s, &c);
    float br = bm[m] * c, bi = bm[m] * s;
    if (seg < 3) {
      int h = m >> 6, d = m & 63;
      qkvBias[seg * 1024 + h * 128 + d] = br;
      qkvBias[seg * 1024 + h * 128 + 64 + d] = bi;
    } else {
      oBias[m] = br;
      oBias[512 + m] = bi;
    }
    return;
  }
  int gid = bx * 256 + threadIdx.x;
  int seg = gid >> 18;
  int id = gid & 262143;
  const float* lm = seg == 0 ? qlm : seg == 1 ? klm : seg == 2 ? vlm : olm;
  const float* ph = seg == 0 ? qph : seg == 1 ? kph : seg == 2 ? vph : oph;
  float mm = __expf(lm[id]);
  float s, c;
  __sincosf(ph[id], &s, &c);
  float wr = mm * c, wi = mm * s;
  int m = id >> 9, k = id & 511;
  if (seg < 3) {
    int h = m >> 6, d = m & 63;
    size_t rowR = (size_t)seg * 1024 + h * 128 + d;
    size_t rowI = rowR + 64;
    Wqkv[rowR * 1024 + k] = f2bf(wr);
    Wqkv[rowR * 1024 + 512 + k] = f2bf(-wi);
    Wqkv[rowI * 1024 + k] = f2bf(wi);
    Wqkv[rowI * 1024 + 512 + k] = f2bf(wr);
  } else {
    Wo[(size_t)m * 1024 + k] = f2bf(wr);
    Wo[(size_t)m * 1024 + 512 + k] = f2bf(-wi);
    Wo[(size_t)(512 + m) * 1024 + k] = f2bf(wi);
    Wo[(size_t)(512 + m) * 1024 + 512 + k] = f2bf(wr);
  }
}

// ---------------------------------------------------------------------------
// Fused build B, 2 elements/thread, packed stores. grid 6144 x 256.
// seg = gid>>19: 0=gate,1=up,2=down.
// Wgu role-in-j: feature T -> row (T>>4)*64 + role*16 + (T&15).
// Wd: K interleaved (hr,hi) pairs.
// ---------------------------------------------------------------------------
__global__ __launch_bounds__(256) void build_wB_kernel(
    const float* __restrict__ glm, const float* __restrict__ gph,
    const float* __restrict__ ulm, const float* __restrict__ uph,
    const float* __restrict__ dlm, const float* __restrict__ dph,
    unsigned short* __restrict__ Wgu, unsigned short* __restrict__ Wd) {
  int gid = blockIdx.x * 256 + threadIdx.x;
  int seg = gid >> 19;
  int id0 = (gid & 524287) * 2;
  const float* lm = seg == 0 ? glm : seg == 1 ? ulm : dlm;
  const float* ph = seg == 0 ? gph : seg == 1 ? uph : dph;
  float2 lm2 = *(const float2*)&lm[id0];
  float2 ph2 = *(const float2*)&ph[id0];
  float m0 = __expf(lm2.x), m1 = __expf(lm2.y);
  float s0, c0, s1, c1;
  __sincosf(ph2.x, &s0, &c0);
  __sincosf(ph2.y, &s1, &c1);
  float wr0 = m0 * c0, wi0 = m0 * s0;
  float wr1 = m1 * c1, wi1 = m1 * s1;
  if (seg < 2) {
    int T = id0 >> 9, k = id0 & 511;
    size_t base = (size_t)(T >> 4) * 64 + (T & 15);
    size_t rR = base + (seg * 2 + 0) * 16;
    size_t rI = base + (seg * 2 + 1) * 16;
    *(unsigned int*)&Wgu[rR * 1024 + k] = pack2(f2bf(wr0), f2bf(wr1));
    *(unsigned int*)&Wgu[rR * 1024 + 512 + k] = pack2(f2bf(-wi0), f2bf(-wi1));
    *(unsigned int*)&Wgu[rI * 1024 + k] = pack2(f2bf(wi0), f2bf(wi1));
    *(unsigned int*)&Wgu[rI * 1024 + 512 + k] = pack2(f2bf(wr0), f2bf(wr1));
  } else {
    int m = id0 >> 11, j = id0 & 2047;
    ushort4 a;
    a.x = f2bf(wr0); a.y = f2bf(-wi0); a.z = f2bf(wr1); a.w = f2bf(-wi1);
    *(ushort4*)&Wd[(size_t)m * 4096 + 2 * j] = a;
    ushort4 b;
    b.x = f2bf(wi0); b.y = f2bf(wr0); b.z = f2bf(wi1); b.w = f2bf(wr1);
    *(ushort4*)&Wd[(size_t)(512 + m) * 4096 + 2 * j] = b;
  }
}

// ---------------------------------------------------------------------------
// Complex LayerNorm (LN2): one WAVE per token. fp32 in -> bf16 (N,1024).
// ---------------------------------------------------------------------------
__global__ __launch_bounds__(256) void cln_kernel(
    const float* __restrict__ xr, const float* __restrict__ xi, int stride,
    const float* __restrict__ g_r, const float* __restrict__ g_i,
    const float* __restrict__ b_r, const float* __restrict__ b_i,
    unsigned short* __restrict__ out) {
  int w = threadIdx.x >> 6, lane = threadIdx.x & 63;
  int t = blockIdx.x * 4 + w;
  int d0 = lane * 8;
  const float* xrt = xr + (size_t)t * stride + d0;
  const float* xit = xi + (size_t)t * stride + d0;
  float4 a0 = *(const float4*)&xrt[0];
  float4 a1 = *(const float4*)&xrt[4];
  float4 c0 = *(const float4*)&xit[0];
  float4 c1 = *(const float4*)&xit[4];

  float s1 = a0.x + a0.y + a0.z + a0.w + a1.x + a1.y + a1.z + a1.w;
  float s2 = c0.x + c0.y + c0.z + c0.w + c1.x + c1.y + c1.z + c1.w;
#pragma unroll
  for (int off = 1; off < 64; off <<= 1) {
    s1 += __shfl_xor(s1, off);
    s2 += __shfl_xor(s2, off);
  }
  float mr = s1 * (1.f / kD), mi = s2 * (1.f / kD);

  float ar[8] = {a0.x, a0.y, a0.z, a0.w, a1.x, a1.y, a1.z, a1.w};
  float ai[8] = {c0.x, c0.y, c0.z, c0.w, c1.x, c1.y, c1.z, c1.w};
  float v = 0.f;
#pragma unroll
  for (int e = 0; e < 8; e++) {
    float cr = ar[e] - mr, ci = ai[e] - mi;
    v += cr * cr + ci * ci;
  }
#pragma unroll
  for (int off = 1; off < 64; off <<= 1) v += __shfl_xor(v, off);
  float inv = rsqrtf(v * (1.f / kD) + 1e-6f);

  unsigned short pr[8], pi[8];
#pragma unroll
  for (int e = 0; e < 8; e++) {
    float nr = (ar[e] - mr) * inv;
    float ni = (ai[e] - mi) * inv;
    pr[e] = f2bf(nr * g_r[d0 + e] - ni * g_i[d0 + e] + b_r[d0 + e]);
    pi[e] = f2bf(nr * g_i[d0 + e] + ni * g_r[d0 + e] + b_i[d0 + e]);
  }
  unsigned short* ot = out + (size_t)t * 1024 + d0;
  *(bf16x8*)&ot[0] = *(const bf16x8*)pr;
  *(bf16x8*)&ot[512] = *(const bf16x8*)pi;
}

// ---------------------------------------------------------------------------
// bf16 MFMA GEMM, 128x128 tile, 4 waves. BK=64 counted-vmcnt double buffer.
// R8: + XCD-aware block swizzle (T1): contiguous linear-id chunks per XCD
// so same-token-tile blocks share the X panel in one L2 (grid 768 % 8 == 0).
// Epilogue modes: 3 = QKV (rope fused, V transposed).
// ---------------------------------------------------------------------------
__global__ __launch_bounds__(256) void cgemm_mfma_kernel(
    const unsigned short* __restrict__ X, int ldx,
    const unsigned short* __restrict__ Wt, int K,
    const float* __restrict__ bias, int mode,
    unsigned short* __restrict__ outb, int ldo,
    unsigned short* __restrict__ vtb) {
  __shared__ unsigned short Sh[32768];  // 64 KB: dbuf x {Xs 8192 | Ws 8192}

  const int tid = threadIdx.x;
  const int w = tid >> 6;
  const int lane = tid & 63;
  const int quad = lane >> 4;
  const int l15 = lane & 15;
  // T1 XCD swizzle (bijective: nwg % 8 == 0)
  const int nwg = gridDim.x * gridDim.y;
  const int lb = blockIdx.y * gridDim.x + blockIdx.x;
  const int sb = (lb & 7) * (nwg >> 3) + (lb >> 3);
  const int m0 = (sb % gridDim.x) * 128;
  const int n0 = (sb / gridDim.x) * 128;
  const int wm = (w & 1) * 64;
  const int wn = (w >> 1) * 64;

  const int rsub = lane >> 3;                    // 0..7
  const int grow = w * 32 + rsub;                // + t*8 per inst
  const int gcol = ((lane & 7) ^ rsub) * 8;      // swizzled global granule
  const unsigned short* gx = X + (size_t)(n0 + grow) * ldx + gcol;
  const unsigned short* gw = Wt + (size_t)(m0 + grow) * K + gcol;

  const int rg = (l15 & 7);                      // read-side swizzle key

  f32x4 acc[4][4];
#pragma unroll
  for (int i = 0; i < 4; i++)
#pragma unroll
    for (int j = 0; j < 4; j++) acc[i][j] = (f32x4){0.f, 0.f, 0.f, 0.f};

  auto stage_tile = [&](int kt, int bsel) {
    const int k0 = kt * 64;
    unsigned short* dX = &Sh[bsel * 16384 + w * 2048];
    unsigned short* dW = &Sh[bsel * 16384 + 8192 + w * 2048];
#pragma unroll
    for (int t = 0; t < 4; t++) {
      __builtin_amdgcn_global_load_lds((const AS1 void*)(gx + (size_t)t * 8 * ldx + k0),
                                       (AS3 void*)(dX + t * 512), 16, 0, 0);
      __builtin_amdgcn_global_load_lds((const AS1 void*)(gw + (size_t)t * 8 * K + k0),
                                       (AS3 void*)(dW + t * 512), 16, 0, 0);
    }
  };

  const int nt = K >> 6;
  stage_tile(0, 0);
  for (int t = 0; t < nt; ++t) {
    if (t + 1 < nt) {
      stage_tile(t + 1, (t + 1) & 1);
      asm volatile("s_waitcnt vmcnt(8)" ::: "memory");
    } else {
      asm volatile("s_waitcnt vmcnt(0)" ::: "memory");
    }
    BARC();  // tile t's loads complete & visible
    const unsigned short* Xs = &Sh[(t & 1) * 16384];
    const unsigned short* Ws = &Sh[(t & 1) * 16384 + 8192];
#pragma unroll
    for (int ks = 0; ks < 2; ks++) {
      const int gsel = ((ks * 4 + quad) ^ rg) * 8;
      bf16x8 af[4], bf[4];
#pragma unroll
      for (int t2 = 0; t2 < 4; t2++) {
        af[t2] = *(const bf16x8*)&Xs[(wn + t2 * 16 + l15) * 64 + gsel];
        bf[t2] = *(const bf16x8*)&Ws[(wm + t2 * 16 + l15) * 64 + gsel];
      }
#pragma unroll
      for (int i = 0; i < 4; i++)
#pragma unroll
        for (int j = 0; j < 4; j++)
          acc[i][j] = __builtin_amdgcn_mfma_f32_16x16x32_bf16(af[i], bf[j], acc[i][j], 0, 0, 0);
    }
    BARC();  // protect buf (t+1)&1 from restage before all reads done
  }

  // ---- epilogue; D mapping: col=lane&15 (feature), row=(lane>>4)*4+reg ----
  if (mode == 3 && m0 < 2048) {
    // q/k: bias + fused RoPE (angle-addition)
#pragma unroll
    for (int j = 0; j < 4; ++j) {
      float bv = bias[m0 + wm + j * 16 + l15];
#pragma unroll
      for (int i = 0; i < 4; ++i)
#pragma unroll
        for (int r = 0; r < 4; ++r) acc[i][j][r] += bv;
    }
    const int sbase = ((n0 + wn) & (kS - 1)) + quad * 4;
#pragma unroll
    for (int j01 = 0; j01 < 2; ++j01) {
      float fi = (float)(j01 * 16 + l15);
      float f = __expf(fi * -0.28782313662425572f);  // -ln(10000)/32
      float c1, s1, c16, s16, cI, sI;
      __sincosf(f, &s1, &c1);
      __sincosf(16.f * f, &s16, &c16);
      __sincosf((float)sbase * f, &sI, &cI);
#pragma unroll
      for (int i = 0; i < 4; ++i) {
        float cc = cI, ss = sI;
#pragma unroll
        for (int r = 0; r < 4; ++r) {
          float x0 = acc[i][j01][r], x1 = acc[i][j01 + 2][r];
          acc[i][j01][r] = x0 * cc - x1 * ss;
          acc[i][j01 + 2][r] = x1 * cc + x0 * ss;
          float cn = cc * c1 - ss * s1;
          ss = ss * c1 + cc * s1;
          cc = cn;
        }
        float cn = cI * c16 - sI * s16;
        sI = sI * c16 + cI * s16;
        cI = cn;
      }
    }
#pragma unroll
    for (int j = 0; j < 4; ++j) {
      int col = m0 + wm + j * 16 + l15;
#pragma unroll
      for (int i = 0; i < 4; ++i) {
        int row0 = n0 + wn + i * 16 + quad * 4;
#pragma unroll
        for (int r = 0; r < 4; ++r)
          outb[(size_t)(row0 + r) * ldo + col] = f2bf(acc[i][j][r]);
      }
    }
  } else {
    // V: LDS-staged transpose, two wave-parity passes. Ts = 64 x 130 shorts.
    unsigned short* Ts = Sh;
#pragma unroll
    for (int p = 0; p < 2; ++p) {
      __syncthreads();
      if ((w & 1) == p) {
#pragma unroll
        for (int j = 0; j < 4; ++j) {
          float bv = bias[m0 + wm + j * 16 + l15];
          int fl = j * 16 + l15;
#pragma unroll
          for (int i = 0; i < 4; ++i) {
            int tk = wn + i * 16 + quad * 4;
#pragma unroll
            for (int r = 0; r < 4; ++r)
              Ts[fl * 130 + tk + r] = f2bf(acc[i][j][r] + bv);
          }
        }
      }
      __syncthreads();
      {
        int fr = tid >> 2, seg = tid & 3;
        int f = (m0 - 2048) + p * 64 + fr;
        int hh = f >> 7, dc = f & 127;
        int bb = n0 >> 10, sbase2 = (n0 & (kS - 1)) + seg * 32;
        unsigned short* dst = &vtb[(size_t)((bb * 8 + hh) * 128 + dc) * 1024 + sbase2];
        const unsigned short* src = &Ts[fr * 130 + seg * 32];
#pragma unroll
        for (int u = 0; u < 4; u++)
          *(bf16x8*)(dst + u * 8) = *(const bf16x8*)(src + u * 8);
      }
    }
  }
}

// ---------------------------------------------------------------------------
// 256x256-tile bf16 MFMA GEMM for gate+up (mode-4 epilogue fused).
// R4 version (best measured): 8-phase schedule, 8 waves, chunk-granular
// staging, counted vmcnt(4), setprio around MFMA quadrants. (No swizzle:
// measured-best version left untouched.)
// ---------------------------------------------------------------------------
__global__ __launch_bounds__(512, 2) void cgemm_mfma_gu256_kernel(
    const unsigned short* __restrict__ X, int ldx,
    const unsigned short* __restrict__ Wt, int K,
    unsigned short* __restrict__ outb, int ldo) {
  __shared__ unsigned short Sh[65536];  // 128 KiB: per buf {X 256x64 | W 256x64}

  const int tid = threadIdx.x;
  const int w = tid >> 6;           // 0..7
  const int lane = tid & 63;
  const int quad = lane >> 4;
  const int l15 = lane & 15;
  const int m0 = blockIdx.x * 256;  // features
  const int n0 = blockIdx.y * 256;  // tokens
  const int wfeat = w & 1;          // feature half (128 wide)
  const int wtok = w >> 1;          // token quarter (64 wide)
  const int swz = l15 & 7;          // read-side swizzle key (= row & 7)

  const int srow = lane >> 3;                     // 0..7
  const int sgran = ((lane & 7) ^ srow) * 8;      // pre-swizzled global granule

  f32x4 acc[4][8];
#pragma unroll
  for (int i = 0; i < 4; i++)
#pragma unroll
    for (int j = 0; j < 8; j++) acc[i][j] = (f32x4){0.f, 0.f, 0.f, 0.f};

  // chunk: 0=X-lo, 1=X-hi, 2=W-lo, 3=W-hi (128 rows x 64 cols, 2 loads/thread)
  auto stage_chunk = [&](int kt, int which) {
    const int k0 = kt * 64;
    const int bsel = kt & 1;
    const int half = which & 1;
    if (which < 2) {
      const unsigned short* g =
          X + (size_t)(n0 + half * 128 + w * 16 + srow) * ldx + k0 + sgran;
      unsigned short* d = &Sh[bsel * 32768 + (half * 128 + w * 16) * 64];
#pragma unroll
      for (int u = 0; u < 2; ++u)
        __builtin_amdgcn_global_load_lds((const AS1 void*)(g + (size_t)u * 8 * ldx),
                                         (AS3 void*)(d + u * 512), 16, 0, 0);
    } else {
      const unsigned short* g =
          Wt + (size_t)(m0 + half * 128 + w * 16 + srow) * K + k0 + sgran;
      unsigned short* d = &Sh[bsel * 32768 + 16384 + (half * 128 + w * 16) * 64];
#pragma unroll
      for (int u = 0; u < 2; ++u)
        __builtin_amdgcn_global_load_lds((const AS1 void*)(g + (size_t)u * 8 * K),
                                         (AS3 void*)(d + u * 512), 16, 0, 0);
    }
  };

  bf16x8 af[4][2];
  bf16x8 bq[4];

  auto read_bq = [&](const unsigned short* Bs, int ks, int jh) {
#pragma unroll
    for (int jj = 0; jj < 4; ++jj)
      bq[jj] = *(const bf16x8*)&Bs[(wfeat * 128 + jh * 64 + jj * 16 + l15) * 64 +
                                   (((ks * 4 + quad) ^ swz) * 8)];
  };

  auto mfma_quad = [&](int ks, int jh) {
    __builtin_amdgcn_s_barrier();
    __builtin_amdgcn_s_setprio(1);
#pragma unroll
    for (int i = 0; i < 4; ++i)
#pragma unroll
      for (int jj = 0; jj < 4; ++jj)
        acc[i][jh * 4 + jj] = __builtin_amdgcn_mfma_f32_16x16x32_bf16(
            af[i][ks], bq[jj], acc[i][jh * 4 + jj], 0, 0, 0);
    __builtin_amdgcn_s_setprio(0);
    __builtin_amdgcn_s_barrier();
  };

  const int nt = K >> 6;  // 16
  // prologue: tile0 all 4 chunks + tile1 X chunks; wait tile0 landed
  stage_chunk(0, 0); stage_chunk(0, 1); stage_chunk(0, 2); stage_chunk(0, 3);
  stage_chunk(1, 0); stage_chunk(1, 1);
  asm volatile("s_waitcnt vmcnt(4)" ::: "memory");
  __builtin_amdgcn_s_barrier();

  for (int t = 0; t < nt; ++t) {
    const unsigned short* As = &Sh[(t & 1) * 32768];
    const unsigned short* Bs = &Sh[(t & 1) * 32768 + 16384];

    // ---- p0: (ks0, jh0); read ALL af ----
#pragma unroll
    for (int i = 0; i < 4; ++i)
#pragma unroll
      for (int ks = 0; ks < 2; ++ks)
        af[i][ks] = *(const bf16x8*)&As[(wtok * 64 + i * 16 + l15) * 64 +
                                        (((ks * 4 + quad) ^ swz) * 8)];
    read_bq(Bs, 0, 0);
    if (t + 1 < nt) stage_chunk(t + 1, 2);
    mfma_quad(0, 0);
#pragma unroll
    for (int i = 0; i < 4; ++i) asm volatile("" :: "v"(af[i][1]));

    // ---- p1: (ks0, jh1) ----
    read_bq(Bs, 0, 1);
    if (t + 1 < nt) stage_chunk(t + 1, 3);
    mfma_quad(0, 1);

    // ---- p2: (ks1, jh0) ----
    read_bq(Bs, 1, 0);
    if (t + 2 < nt) stage_chunk(t + 2, 0);
    mfma_quad(1, 0);

    // ---- p3: (ks1, jh1) ----
    read_bq(Bs, 1, 1);
    if (t + 2 < nt) {
      stage_chunk(t + 2, 1);
      asm volatile("s_waitcnt vmcnt(4)" ::: "memory");
    } else {
      asm volatile("s_waitcnt vmcnt(0)" ::: "memory");
    }
    mfma_quad(1, 1);
  }

  // ---- gating epilogue; role-in-j: j=0..3 role group jh=0, j=4..7 jh=1 ----
#pragma unroll
  for (int i = 0; i < 4; ++i) {
    int row0 = n0 + wtok * 64 + i * 16 + quad * 4;
#pragma unroll
    for (int jh = 0; jh < 2; ++jh) {
      int T = ((m0 + wfeat * 128 + jh * 64) >> 6) * 16 + l15;
#pragma unroll
      for (int r = 0; r < 4; ++r) {
        float gr = acc[i][jh * 4 + 0][r], gi = acc[i][jh * 4 + 1][r];
        float ur = acc[i][jh * 4 + 2][r], ui = acc[i][jh * 4 + 3][r];
        float sg = __builtin_amdgcn_rcpf(1.f + __expf(-sqrtf(gr * gr + gi * gi)));
        float gar = gr * sg, gai = gi * sg;
        unsigned int pk = pack2(f2bf(gar * ur - gai * ui), f2bf(gar * ui + gai * ur));
        *(unsigned int*)&outb[(size_t)(row0 + r) * ldo + 2 * T] = pk;
      }
    }
  }
}

// ---------------------------------------------------------------------------
// bf16 MFMA GEMM, 64x128 tile, 4 waves. BK=64 counted-vmcnt double buffer
// (R6 form, K-split REVERTED). R8: + XCD-aware block swizzle (T1) — the down
// GEMM's 8 feature-tiles re-read the full X panel; contiguous per-XCD chunks
// (8 feat x 8 token tiles) make those reads L2-shared instead of duplicated
// across XCDs (R7 counters: FETCH 148 MB vs 40 MB inputs). grid 512 % 8 == 0.
// fp32 epilogues: 1 = O-proj (+bias +x residual), 2 = down (+res -> d_out).
// ---------------------------------------------------------------------------
__global__ __launch_bounds__(256) void cgemm_mfma_n64_kernel(
    const unsigned short* __restrict__ X, int ldx,
    const unsigned short* __restrict__ Wt, int K,
    const float* __restrict__ bias, int mode,
    const float* __restrict__ resr, const float* __restrict__ resi,
    float* __restrict__ outf) {
  __shared__ unsigned short Sh[24576];  // 48 KB: {X0|W0|X1|W1}, 12288 shorts/buf

  const int tid = threadIdx.x;
  const int w = tid >> 6;
  const int lane = tid & 63;
  const int quad = lane >> 4;
  const int l15 = lane & 15;
  // T1 XCD swizzle (bijective: nwg % 8 == 0)
  const int nwg = gridDim.x * gridDim.y;
  const int lb = blockIdx.y * gridDim.x + blockIdx.x;
  const int sb = (lb & 7) * (nwg >> 3) + (lb >> 3);
  const int m0 = (sb % gridDim.x) * 128;
  const int n0 = (sb / gridDim.x) * 64;
  const int wm = (w & 1) * 64;
  const int wn = (w >> 1) * 32;
  const int swz = l15 & 7;

  // staging: per gload a wave covers 8 rows x 8 granules (swizzled source)
  const int srow = lane >> 3;
  const int sgran = ((lane & 7) ^ srow) * 8;
  const unsigned short* gX = X + (size_t)(n0 + w * 16 + srow) * ldx + sgran;
  const unsigned short* gW = Wt + (size_t)(m0 + w * 32 + srow) * K + sgran;

  f32x4 acc[2][4];
#pragma unroll
  for (int i = 0; i < 2; i++)
#pragma unroll
    for (int j = 0; j < 4; j++) acc[i][j] = (f32x4){0.f, 0.f, 0.f, 0.f};

  auto stage_tile = [&](int kt, int bsel) {
    const int k0 = kt * 64;
    unsigned short* dX = &Sh[bsel * 12288 + w * 1024];         // 16 rows/wave
    unsigned short* dW = &Sh[bsel * 12288 + 4096 + w * 2048];  // 32 rows/wave
#pragma unroll
    for (int u = 0; u < 2; ++u)
      __builtin_amdgcn_global_load_lds((const AS1 void*)(gX + (size_t)u * 8 * ldx + k0),
                                       (AS3 void*)(dX + u * 512), 16, 0, 0);
#pragma unroll
    for (int u = 0; u < 4; ++u)
      __builtin_amdgcn_global_load_lds((const AS1 void*)(gW + (size_t)u * 8 * K + k0),
                                       (AS3 void*)(dW + u * 512), 16, 0, 0);
  };

  const int nt = K >> 6;
  stage_tile(0, 0);
  for (int t = 0; t < nt; ++t) {
    if (t + 1 < nt) {
      stage_tile(t + 1, (t + 1) & 1);
      asm volatile("s_waitcnt vmcnt(6)" ::: "memory");
    } else {
      asm volatile("s_waitcnt vmcnt(0)" ::: "memory");
    }
    BARC();  // tile t's loads complete & visible
    const unsigned short* Xs = &Sh[(t & 1) * 12288];
    const unsigned short* Ws = &Sh[(t & 1) * 12288 + 4096];
#pragma unroll
    for (int ks = 0; ks < 2; ++ks) {
      const int gsel = ((ks * 4 + quad) ^ swz) * 8;
      bf16x8 af[2], bf[4];
#pragma unroll
      for (int t2 = 0; t2 < 2; ++t2)
        af[t2] = *(const bf16x8*)&Xs[(wn + t2 * 16 + l15) * 64 + gsel];
#pragma unroll
      for (int t2 = 0; t2 < 4; ++t2)
        bf[t2] = *(const bf16x8*)&Ws[(wm + t2 * 16 + l15) * 64 + gsel];
#pragma unroll
      for (int i = 0; i < 2; i++)
#pragma unroll
        for (int j = 0; j < 4; j++)
          acc[i][j] = __builtin_amdgcn_mfma_f32_16x16x32_bf16(af[i], bf[j], acc[i][j], 0, 0, 0);
    }
    BARC();  // protect buf (t+1)&1 from being restaged before all reads done
  }

#pragma unroll
  for (int j = 0; j < 4; ++j) {
    int col = m0 + wm + j * 16 + l15;
    float bv = bias ? bias[col] : 0.f;
#pragma unroll
    for (int i = 0; i < 2; ++i) {
      int row0 = n0 + wn + i * 16 + quad * 4;
#pragma unroll
      for (int r = 0; r < 4; ++r) {
        int row = row0 + r;
        float val = acc[i][j][r] + bv;
        if (mode == 1) {
          float xres = (col < 512) ? resr[(size_t)row * 512 + col]
                                   : resi[(size_t)row * 512 + col - 512];
          outf[(size_t)row * 1024 + col] = val + xres;
        } else {
          float rv = resr[(size_t)row * 1024 + col] + val;
          size_t dd = (col < 512) ? ((size_t)row * 512 + col)
                                  : ((size_t)kBSD + (size_t)row * 512 + (col - 512));
          outf[dd] = rv;
        }
      }
    }
  }
}

// ---------------------------------------------------------------------------
// MFMA flash attention (causal, Hermitian). K-tile = 64.
// T14 async-STAGE split: K/V tile kt+1 prefetched into 32 registers before
// compute of tile kt; reg->LDS writes at top of next iteration (raw barrier
// + explicit lgkmcnt(0) so the in-flight global loads are not drained).
// LDS: Ks 64x136 + Vs 128x72 + Ps 4x16x72 = 45,056 B.
// ---------------------------------------------------------------------------
__global__ __launch_bounds__(256) void attn_mfma_kernel(
    const unsigned short* __restrict__ qkv,   // (4096, 3072)
    const unsigned short* __restrict__ vt,    // (4,8,128,1024)
    unsigned short* __restrict__ out) {       // (4096, 1024) [ar|ai]
  __shared__ unsigned short Ks[64 * 136];
  __shared__ unsigned short Vs[128 * 72];
  __shared__ unsigned short Ps[4 * 16 * 72];

  const int tid = threadIdx.x;
  const int w = tid >> 6;
  const int lane = tid & 63;
  const int quad = lane >> 4;
  const int l15 = lane & 15;

  int bid = blockIdx.x;
  int second = bid >> 8;             // 0: blocks 0..255, 1: 256..511
  int u = bid & 255;
  int t_ = u & 15;
  const int qt = second ? (15 - t_) : t_;   // complementary across halves
  const int h = (u >> 4) & 7;
  const int b = second * 2 + (u >> 7);
  const int q0 = qt * 64;
  const int wrow0 = q0 + w * 16;

  bf16x8 qa[4];
  {
    size_t base = (size_t)(b * kS + wrow0 + l15) * 3072 + h * 128;
#pragma unroll
    for (int ks = 0; ks < 4; ks++)
      qa[ks] = *(const bf16x8*)&qkv[base + ks * 32 + quad * 8];
  }

  f32x4 oacc[8];
#pragma unroll
  for (int dt = 0; dt < 8; dt++) oacc[dt] = (f32x4){0.f, 0.f, 0.f, 0.f};
  float m_r[4] = {-1e30f, -1e30f, -1e30f, -1e30f};
  float l_r[4] = {0.f, 0.f, 0.f, 0.f};

  const int nkt = qt + 1;
  const float cexp = 0.1803368801f;  // (1/sqrt(64)) * log2(e)

  const unsigned short* gkbase = qkv + 1024 + h * 128;
  const unsigned short* gvbase = vt + (size_t)((b * 8 + h) * 128) * 1024;

  const int ch = tid * 4;
  bf16x8 kreg[4], vreg[4];
  auto load_kv = [&](int k0) {
    const unsigned short* gk = gkbase + (size_t)(b * kS + k0) * 3072;
#pragma unroll
    for (int u2 = 0; u2 < 4; u2++) {
      int idx = ch + u2, r = idx >> 4, cc = (idx & 15) * 8;
      kreg[u2] = *(const bf16x8*)&gk[(size_t)r * 3072 + cc];
    }
#pragma unroll
    for (int u2 = 0; u2 < 4; u2++) {
      int idx = ch + u2, vr = idx >> 3, vc = (idx & 7) * 8;
      vreg[u2] = *(const bf16x8*)&gvbase[(size_t)vr * 1024 + k0 + vc];
    }
  };

  load_kv(0);

  for (int kt = 0; kt < nkt; ++kt) {
    const int k0 = kt * 64;
    BARC();  // all waves done reading Ks/Vs from the previous tile
    // write the prefetched tile to LDS (compiler inserts the vmcnt waits
    // for kreg/vreg defs right here — exactly where they are needed)
#pragma unroll
    for (int u2 = 0; u2 < 4; u2++) {
      int idx = ch + u2, r = idx >> 4, cc = (idx & 15) * 8;
      *(bf16x8*)&Ks[r * 136 + cc] = kreg[u2];
    }
#pragma unroll
    for (int u2 = 0; u2 < 4; u2++) {
      int idx = ch + u2, vr = idx >> 3, vc = (idx & 7) * 8;
      *(bf16x8*)&Vs[vr * 72 + vc] = vreg[u2];
    }
    // kick next tile's global loads — they fly during compute below
    if (kt + 1 < nkt) load_kv(k0 + 64);
    asm volatile("s_waitcnt lgkmcnt(0)" ::: "memory");  // ds_writes complete
    BARC();  // Ks/Vs visible to all waves; prefetch NOT drained

    f32x4 s[4];
#pragma unroll
    for (int ns = 0; ns < 4; ns++) {
      s[ns] = (f32x4){0.f, 0.f, 0.f, 0.f};
#pragma unroll
      for (int ks = 0; ks < 4; ks++) {
        bf16x8 kb = *(const bf16x8*)&Ks[(ns * 16 + l15) * 136 + ks * 32 + quad * 8];
        s[ns] = __builtin_amdgcn_mfma_f32_16x16x32_bf16(qa[ks], kb, s[ns], 0, 0, 0);
      }
    }

    if (k0 + 63 > wrow0) {
#pragma unroll
      for (int r = 0; r < 4; r++) {
        int qrow = wrow0 + quad * 4 + r;
#pragma unroll
        for (int ns = 0; ns < 4; ns++)
          if (k0 + ns * 16 + l15 > qrow) s[ns][r] = -1e30f;
      }
    }

    float alpha[4];
#pragma unroll
    for (int r = 0; r < 4; r++) {
      float mx = fmaxf(fmaxf(s[0][r], s[1][r]), fmaxf(s[2][r], s[3][r]));
      mx = fmaxf(mx, __shfl_xor(mx, 1));
      mx = fmaxf(mx, __shfl_xor(mx, 2));
      mx = fmaxf(mx, __shfl_xor(mx, 4));
      mx = fmaxf(mx, __shfl_xor(mx, 8));
      float mn = fmaxf(m_r[r], mx);
      float al = exp2f((m_r[r] - mn) * cexp);
      m_r[r] = mn;
      float rs = 0.f;
#pragma unroll
      for (int ns = 0; ns < 4; ns++) {
        float p = exp2f((s[ns][r] - mn) * cexp);
        s[ns][r] = p;
        rs += p;
      }
      rs += __shfl_xor(rs, 1);
      rs += __shfl_xor(rs, 2);
      rs += __shfl_xor(rs, 4);
      rs += __shfl_xor(rs, 8);
      l_r[r] = l_r[r] * al + rs;
      alpha[r] = al;
    }

#pragma unroll
    for (int dt = 0; dt < 8; dt++)
#pragma unroll
      for (int r = 0; r < 4; r++) oacc[dt][r] *= alpha[r];

    unsigned short* pw = &Ps[w * 1152];
#pragma unroll
    for (int r = 0; r < 4; r++) {
      int q = quad * 4 + r;
#pragma unroll
      for (int ns = 0; ns < 4; ns++)
        pw[q * 72 + ns * 16 + l15] = f2bf(s[ns][r]);
    }
    bf16x8 pa0 = *(const bf16x8*)&pw[l15 * 72 + quad * 8];
    bf16x8 pa1 = *(const bf16x8*)&pw[l15 * 72 + 32 + quad * 8];

#pragma unroll
    for (int dt = 0; dt < 8; dt++) {
      bf16x8 vb0 = *(const bf16x8*)&Vs[(dt * 16 + l15) * 72 + quad * 8];
      bf16x8 vb1 = *(const bf16x8*)&Vs[(dt * 16 + l15) * 72 + 32 + quad * 8];
      oacc[dt] = __builtin_amdgcn_mfma_f32_16x16x32_bf16(pa0, vb0, oacc[dt], 0, 0, 0);
      oacc[dt] = __builtin_amdgcn_mfma_f32_16x16x32_bf16(pa1, vb1, oacc[dt], 0, 0, 0);
    }
  }

  float inv[4];
#pragma unroll
  for (int r = 0; r < 4; r++) inv[r] = __builtin_amdgcn_rcpf(l_r[r]);
#pragma unroll
  for (int dt = 0; dt < 8; dt++) {
    int dcat = dt * 16 + l15;
    int col = (dcat < 64) ? (h * 64 + dcat) : (512 + h * 64 + dcat - 64);
#pragma unroll
    for (int r = 0; r < 4; r++) {
      int tok = b * kS + wrow0 + quad * 4 + r;
      out[(size_t)tok * 1024 + col] = f2bf(oacc[dt][r] * inv[r]);
    }
  }
}

// ---------------------------------------------------------------------------
// Launcher
// ---------------------------------------------------------------------------
extern "C" void kernel_launch(void* const* d_in, const int* in_sizes, int n_in,
                              void* d_out, int out_size, void* d_ws, size_t ws_size,
                              hipStream_t stream) {
  const float* x_real = (const float*)d_in[0];
  const float* x_imag = (const float*)d_in[1];
  const float* ln1_gr = (const float*)d_in[2];
  const float* ln1_gi = (const float*)d_in[3];
  const float* ln1_br = (const float*)d_in[4];
  const float* ln1_bi = (const float*)d_in[5];
  const float* q_lm = (const float*)d_in[6];
  const float* q_ph = (const float*)d_in[7];
  const float* q_bm = (const float*)d_in[8];
  const float* q_bp = (const float*)d_in[9];
  const float* k_lm = (const float*)d_in[10];
  const float* k_ph = (const float*)d_in[11];
  const float* k_bm = (const float*)d_in[12];
  const float* k_bp = (const float*)d_in[13];
  const float* v_lm = (const float*)d_in[14];
  const float* v_ph = (const float*)d_in[15];
  const float* v_bm = (const float*)d_in[16];
  const float* v_bp = (const float*)d_in[17];
  const float* o_lm = (const float*)d_in[18];
  const float* o_ph = (const float*)d_in[19];
  const float* o_bm = (const float*)d_in[20];
  const float* o_bp = (const float*)d_in[21];
  const float* ln2_gr = (const float*)d_in[22];
  const float* ln2_gi = (const float*)d_in[23];
  const float* ln2_br = (const float*)d_in[24];
  const float* ln2_bi = (const float*)d_in[25];
  const float* gate_lm = (const float*)d_in[26];
  const float* gate_ph = (const float*)d_in[27];
  const float* up_lm = (const float*)d_in[28];
  const float* up_ph = (const float*)d_in[29];
  const float* down_lm = (const float*)d_in[30];
  const float* down_ph = (const float*)d_in[31];

  // ---- workspace layout (bytes) ----
  char* wsb = (char*)d_ws;
  unsigned short* Wqkv = (unsigned short*)(wsb + 0);           // 3072x1024 bf16
  unsigned short* Wo   = (unsigned short*)(wsb + 6291456);     // 1024x1024
  unsigned short* Wgu  = (unsigned short*)(wsb + 8388608);     // 8192x1024 (role-in-j)
  unsigned short* Wd   = (unsigned short*)(wsb + 25165824);    // 1024x4096 (interleaved K)
  float* qkvBias = (float*)(wsb + 33554432);                   // 3072 fp32
  float* oBias   = (float*)(wsb + 33566720);                   // 1024 fp32
  float* res     = (float*)(wsb + 33570816);                   // 4096x1024 fp32
  unsigned short* H = (unsigned short*)(wsb + 50348032);       // 4096x1024 bf16
  char* big = wsb + 58736640;
  unsigned short* qkv     = (unsigned short*)big;              // 4096x3072 bf16
  unsigned short* attnout = (unsigned short*)(big + 25165824); // 4096x1024 bf16
  unsigned short* vtb     = (unsigned short*)(big + 33554432); // 4x8x128x1024 bf16
  unsigned short* hid     = (unsigned short*)big;              // 4096x4096 bf16 (aliases dead bufs)

  float* outf = (float*)d_out;  // (2, 4096, 512)

  // 1) fused builds (wA includes biases + LN1)
  build_wA_kernel<<<5128, 256, 0, stream>>>(q_lm, q_ph, k_lm, k_ph, v_lm, v_ph,
                                            o_lm, o_ph, q_bm, q_bp, k_bm, k_bp,
                                            v_bm, v_bp, o_bm, o_bp,
                                            x_real, x_imag, ln1_gr, ln1_gi,
                                            ln1_br, ln1_bi,
                                            Wqkv, Wo, qkvBias, oBias, H);
  build_wB_kernel<<<6144, 256, 0, stream>>>(gate_lm, gate_ph, up_lm, up_ph,
                                            down_lm, down_ph, Wgu, Wd);

  // 2) QKV fused GEMM (mode 3, counted-vmcnt dbuf + XCD swizzle): V -> vtb
  {
    dim3 g(3072 / 128, kNT / 128);
    cgemm_mfma_kernel<<<g, 256, 0, stream>>>(H, 1024, Wqkv, 1024, qkvBias, 3, qkv, 3072, vtb);
  }

  // 3) attention -> attnout (load-balanced decode, T14 K/V prefetch)
  attn_mfma_kernel<<<kB * kH * (kS / 64), 256, 0, stream>>>(qkv, vtb, attnout);

  // 4) O-proj + x residual -> res fp32 (BK=64 counted-vmcnt dbuf + XCD swizzle)
  {
    dim3 g(1024 / 128, kNT / 64);
    cgemm_mfma_n64_kernel<<<g, 256, 0, stream>>>(attnout, 1024, Wo, 1024, oBias, 1,
                                                 x_real, x_imag, res);
  }

  // 5) LN2: res -> H
  cln_kernel<<<kNT / 4, 256, 0, stream>>>(res, res + 512, 1024, ln2_gr, ln2_gi, ln2_br, ln2_bi, H);

  // 6) gate+up GEMM, 256^2 8-phase counted-vmcnt schedule (best) -> hid
  {
    dim3 g(8192 / 256, kNT / 256);
    cgemm_mfma_gu256_kernel<<<g, 512, 0, stream>>>(H, 1024, Wgu, 1024, hid, 4096);
  }

  // 7) down GEMM + residual -> d_out (BK=64 counted-vmcnt dbuf + XCD swizzle)
  {
    dim3 g(1024 / 128, kNT / 64);
    cgemm_mfma_n64_kernel<<<g, 256, 0, stream>>>(hid, 4096, Wd, 4096, nullptr, 2,
                                                 res, nullptr, outf);
  }
}